// Round 4
// baseline (379.084 us; speedup 1.0000x reference)
//
#include <hip/hip_runtime.h>

// GraphAttentionLayer: out = softmax(mask(beta * cos_sim(x,x), adj)) @ x
// N=8192, D=128, density 0.005 (~41 neighbors/row incl. self-loop).
//
// Sparse formulation: exp(-1e9) == 0.0f exactly in fp32 -> non-neighbors drop
// out. |score| < beta < 1 -> exp can't over/underflow -> no max pass.
//
// R4: (a) scan loses the nontemporal hint (suspected streaming-BW penalty);
//     (b) agg restructured to GROUPED mode: 16 lanes per neighbor, 4
//         neighbors per wave-batch, 8 dims per lane. The wave-wide butterfly
//         (6 shfl/neighbor) becomes 4 swizzle steps amortized over 4
//         neighbors -> ~5x fewer DS ops in the hot loop.

#define GN 8192
#define GD 128
#define WPB 4            // waves (rows) per 256-thread block
#define MAXN 128         // index slots per row (max observed nnz ~80)
#define BUF 160          // LDS compaction buffer per wave (slack, never hit)

typedef float f32x4 __attribute__((ext_vector_type(4)));

__global__ __launch_bounds__(256, 8) void scan_kernel(
    const float* __restrict__ x, const float* __restrict__ adj,
    float* __restrict__ norms, int* __restrict__ cnts, int* __restrict__ idxg) {
    __shared__ int idxb[WPB][BUF];

    int wid = threadIdx.x >> 6, lane = threadIdx.x & 63;
    int row = blockIdx.x * WPB + wid;
    int* my = idxb[wid];
    const float* arow = adj + (size_t)row * GN;

    // fused row-norm (hides under the adj stream's memory waits)
    float2 u = *(const float2*)(x + (size_t)row * GD + lane * 2);
    float ns = u.x * u.x + u.y * u.y;
    #pragma unroll
    for (int m = 32; m; m >>= 1) ns += __shfl_xor(ns, m, 64);
    if (lane == 0) norms[row] = sqrtf(ns);

    // rolling prefetch, 3 chunks (3 KB/wave) in flight
    f32x4 a0 = *(const f32x4*)(arow + 0 * 256 + lane * 4);
    f32x4 a1 = *(const f32x4*)(arow + 1 * 256 + lane * 4);
    f32x4 a2 = *(const f32x4*)(arow + 2 * 256 + lane * 4);

    int cnt = 0;   // wave-uniform (from ballots)
    for (int chunk = 0; chunk < 32; ++chunk) {
        int pc = chunk + 3; if (pc > 31) pc = 31;   // clamped (no branch)
        f32x4 an = *(const f32x4*)(arow + pc * 256 + lane * 4);
        int col0 = chunk * 256 + lane * 4;
        #pragma unroll
        for (int c = 0; c < 4; ++c) {
            bool nz = (a0[c] != 0.f);
            unsigned long long m = __ballot(nz);
            int off = __builtin_amdgcn_mbcnt_hi((unsigned)(m >> 32),
                      __builtin_amdgcn_mbcnt_lo((unsigned)m, 0));
            // branch-free: inactive lanes dump to a trash slot (no exec churn)
            int dst = nz ? cnt + off : BUF - 1;
            my[dst] = col0 + c;
            cnt += __popcll(m);
        }
        a0 = a1; a1 = a2; a2 = an;
    }

    if (cnt > MAXN) cnt = MAXN;   // unreachable safety clamp
    __builtin_amdgcn_wave_barrier();
    int* grow = idxg + (size_t)row * MAXN;
    if (lane < cnt)      grow[lane]      = my[lane];
    if (64 + lane < cnt) grow[64 + lane] = my[64 + lane];
    if (lane == 0) cnts[row] = cnt;
}

__global__ __launch_bounds__(256, 8) void agg_kernel(
    const float* __restrict__ x, const float* __restrict__ beta_p,
    const float* __restrict__ norms, const int* __restrict__ cnts,
    const int* __restrict__ idxg, float* __restrict__ out) {
    __shared__ int idxb[WPB][MAXN + 8];

    int wid = threadIdx.x >> 6, lane = threadIdx.x & 63;
    int row = blockIdx.x * WPB + wid;
    int* my = idxb[wid];

    int cnt = cnts[row];                      // same addr all lanes -> broadcast
    const int* grow = idxg + (size_t)row * MAXN;
    if (lane < cnt)      my[lane]      = grow[lane];
    if (64 + lane < cnt) my[64 + lane] = grow[64 + lane];
    if (lane < 8) my[cnt + lane] = row;       // sentinels for the group tail
    __builtin_amdgcn_wave_barrier();

    int g = lane >> 4;        // group 0..3: one neighbor per group per batch
    int t = lane & 15;        // thread in group: dims 8t .. 8t+7

    const float* xr = x + (size_t)row * GD + t * 8;
    f32x4 u0 = *(const f32x4*)xr;
    f32x4 u1 = *(const f32x4*)(xr + 4);
    float beta = beta_p[0];
    float ni = norms[row];

    f32x4 a0 = {0.f, 0.f, 0.f, 0.f}, a1 = {0.f, 0.f, 0.f, 0.f};
    float dn = 0.f;

    for (int k = 0; k < cnt; k += 4) {
        int j = my[k + g];                    // 4 distinct addrs -> group broadcast
        const float* xj = x + (size_t)j * GD + t * 8;
        f32x4 v0 = *(const f32x4*)xj;         // 512 B contiguous per group
        f32x4 v1 = *(const f32x4*)(xj + 4);
        float d = v0.x * u0.x + v0.y * u0.y + v0.z * u0.z + v0.w * u0.w
                + v1.x * u1.x + v1.y * u1.y + v1.z * u1.z + v1.w * u1.w;
        // reduce within the 16-lane group: 4 swizzle steps, shared by 4 groups
        d += __shfl_xor(d, 8, 64);
        d += __shfl_xor(d, 4, 64);
        d += __shfl_xor(d, 2, 64);
        d += __shfl_xor(d, 1, 64);
        float nj = norms[j];                  // group-uniform gather (4 scalars)
        float s = beta * d * __builtin_amdgcn_rcpf(ni * nj + 1e-7f);
        float p = (k + g < cnt) ? __expf(s) : 0.f;
        dn += p;
        a0.x += p * v0.x; a0.y += p * v0.y; a0.z += p * v0.z; a0.w += p * v0.w;
        a1.x += p * v1.x; a1.y += p * v1.y; a1.z += p * v1.z; a1.w += p * v1.w;
    }

    // combine the 4 groups (lanes l, l^16, l^32, l^48 hold the same dims)
    #pragma unroll
    for (int m = 16; m <= 32; m <<= 1) {
        a0.x += __shfl_xor(a0.x, m, 64); a0.y += __shfl_xor(a0.y, m, 64);
        a0.z += __shfl_xor(a0.z, m, 64); a0.w += __shfl_xor(a0.w, m, 64);
        a1.x += __shfl_xor(a1.x, m, 64); a1.y += __shfl_xor(a1.y, m, 64);
        a1.z += __shfl_xor(a1.z, m, 64); a1.w += __shfl_xor(a1.w, m, 64);
        dn   += __shfl_xor(dn,   m, 64);
    }

    float inv = 1.0f / dn;
    if (g == 0) {                             // 16 lanes write 512 B
        float* orow = out + (size_t)row * GD + t * 8;
        f32x4 o0 = {a0.x * inv, a0.y * inv, a0.z * inv, a0.w * inv};
        f32x4 o1 = {a1.x * inv, a1.y * inv, a1.z * inv, a1.w * inv};
        *(f32x4*)orow = o0;
        *(f32x4*)(orow + 4) = o1;
    }
}

extern "C" void kernel_launch(void* const* d_in, const int* in_sizes, int n_in,
                              void* d_out, int out_size, void* d_ws, size_t ws_size,
                              hipStream_t stream) {
    const float* x    = (const float*)d_in[0];
    const float* adj  = (const float*)d_in[1];
    const float* beta = (const float*)d_in[2];
    float* out = (float*)d_out;

    // ws layout: norms [8192 f] | cnts [8192 i] | idx [8192*128 i] = 4.06 MB
    float* norms = (float*)d_ws;
    int*   cnts  = (int*)((char*)d_ws + GN * sizeof(float));
    int*   idxg  = (int*)((char*)d_ws + 2 * GN * sizeof(float));

    scan_kernel<<<GN / WPB, 256, 0, stream>>>(x, adj, norms, cnts, idxg);
    agg_kernel<<<GN / WPB, 256, 0, stream>>>(x, beta, norms, cnts, idxg, out);
}

// Round 5
// 361.933 us; speedup vs baseline: 1.0474x; 1.0474x over previous
//
#include <hip/hip_runtime.h>

// GraphAttentionLayer: out = softmax(mask(beta * cos_sim(x,x), adj)) @ x
// N=8192, D=128, density 0.005 (~41 neighbors/row incl. self-loop).
//
// Sparse formulation: exp(-1e9) == 0.0f exactly in fp32 -> non-neighbors drop
// out of the softmax. |score| <= beta < 1 (Cauchy-Schwarz) -> exp can't
// over/underflow -> no max-subtraction pass (shift invariance).
//
// R5: ONE fused kernel, one wave per row.
//  - adj row streamed with 3-deep rolling prefetch (1 KB/wave-instr),
//    ballot-compacted (branch-free, mbcnt offsets) into an LDS index buffer;
//  - aggregation INTERLEAVED into the scan loop: as soon as 4 indices are
//    buffered, a 4-neighbor batch is processed (16 lanes/neighbor, 8 dims
//    per lane), hiding VALU/DS work under the adj stream's vmcnt latency;
//  - neighbor norms computed inline from the already-loaded x_j registers
//    (q = v.v rides the same 4-step group butterfly as the dot) -> no norms
//    kernel, no norms array, no idx round-trip, no d_ws use at all.
// Replay budget: harness fills+restores ~250 us HBM + ~80 dispatch gaps;
// our floor = adj read 268 MB ~ 43 us. This kernel targets exactly that.

#define GN 8192
#define GD 128
#define WPB 4            // waves (rows) per 256-thread block
#define BUF 192          // LDS index slots per wave (max nnz ~80 + slack)

typedef float f32x4 __attribute__((ext_vector_type(4)));

__global__ __launch_bounds__(256, 8) void gat_fused(
    const float* __restrict__ x, const float* __restrict__ adj,
    const float* __restrict__ beta_p, float* __restrict__ out) {
    __shared__ int idxb[WPB][BUF];

    int wid = threadIdx.x >> 6, lane = threadIdx.x & 63;
    int row = blockIdx.x * WPB + wid;
    int* my = idxb[wid];

    int g = lane >> 4;        // group 0..3: one neighbor per group per batch
    int t = lane & 15;        // lane-in-group: dims 8t .. 8t+7

    const float* xr = x + (size_t)row * GD + t * 8;
    f32x4 u0 = *(const f32x4*)xr;
    f32x4 u1 = *(const f32x4*)(xr + 4);

    // ||x_i|| inline (4-step group butterfly; all 4 groups redundant-identical)
    float qi = u0.x*u0.x + u0.y*u0.y + u0.z*u0.z + u0.w*u0.w
             + u1.x*u1.x + u1.y*u1.y + u1.z*u1.z + u1.w*u1.w;
    qi += __shfl_xor(qi, 8, 64);
    qi += __shfl_xor(qi, 4, 64);
    qi += __shfl_xor(qi, 2, 64);
    qi += __shfl_xor(qi, 1, 64);
    float ni = sqrtf(qi);

    float beta = beta_p[0];
    const float* arow = adj + (size_t)row * GN;

    f32x4 acc0 = {0.f,0.f,0.f,0.f}, acc1 = {0.f,0.f,0.f,0.f};
    float dn = 0.f;
    int cnt = 0, done = 0;    // both wave-uniform

    // one 4-neighbor batch: 16 lanes per neighbor, dot + norm share butterfly
    auto batch = [&](int k, bool full) {
        int j = my[k + g];                       // 4 addrs -> group broadcast
        const float* xj = x + (size_t)j * GD + t * 8;
        f32x4 v0 = *(const f32x4*)xj;            // 512 B contiguous per group
        f32x4 v1 = *(const f32x4*)(xj + 4);
        float d = v0.x*u0.x + v0.y*u0.y + v0.z*u0.z + v0.w*u0.w
                + v1.x*u1.x + v1.y*u1.y + v1.z*u1.z + v1.w*u1.w;
        float q = v0.x*v0.x + v0.y*v0.y + v0.z*v0.z + v0.w*v0.w
                + v1.x*v1.x + v1.y*v1.y + v1.z*v1.z + v1.w*v1.w;
        d += __shfl_xor(d, 8, 64);  q += __shfl_xor(q, 8, 64);
        d += __shfl_xor(d, 4, 64);  q += __shfl_xor(q, 4, 64);
        d += __shfl_xor(d, 2, 64);  q += __shfl_xor(q, 2, 64);
        d += __shfl_xor(d, 1, 64);  q += __shfl_xor(q, 1, 64);
        float nj = sqrtf(q);                     // inline neighbor norm
        float s = beta * d * __builtin_amdgcn_rcpf(ni * nj + 1e-7f);
        float p = __expf(s);
        p = (full || (k + g < cnt)) ? p : 0.f;   // mask sentinel tail
        dn += p;
        acc0.x += p*v0.x; acc0.y += p*v0.y; acc0.z += p*v0.z; acc0.w += p*v0.w;
        acc1.x += p*v1.x; acc1.y += p*v1.y; acc1.z += p*v1.z; acc1.w += p*v1.w;
    };

    // 3-deep rolling prefetch of the adj row (32 chunks x 1 KB)
    f32x4 c0 = *(const f32x4*)(arow + 0 * 256 + lane * 4);
    f32x4 c1 = *(const f32x4*)(arow + 1 * 256 + lane * 4);
    f32x4 c2 = *(const f32x4*)(arow + 2 * 256 + lane * 4);

    for (int chunk = 0; chunk < 32; ++chunk) {
        int pc = chunk + 3; if (pc > 31) pc = 31;       // clamped (no branch)
        f32x4 nx = *(const f32x4*)(arow + pc * 256 + lane * 4);
        int col0 = chunk * 256 + lane * 4;
        #pragma unroll
        for (int c = 0; c < 4; ++c) {
            bool nz = (c0[c] != 0.f);
            unsigned long long m = __ballot(nz);
            int off = __builtin_amdgcn_mbcnt_hi((unsigned)(m >> 32),
                      __builtin_amdgcn_mbcnt_lo((unsigned)m, 0));
            int dst = nz ? cnt + off : BUF - 1;         // trash slot, no exec churn
            my[dst] = col0 + c;
            cnt += __popcll(m);
        }
        c0 = c1; c1 = c2; c2 = nx;
        __builtin_amdgcn_wave_barrier();

        // interleave: drain completed 4-neighbor batches under the vmcnt shadow
        while (cnt - done >= 4) { batch(done, true); done += 4; }
    }

    // tail (0..3 remaining) with self-index sentinels, predicated off
    if (lane < 4) my[cnt + lane] = row;
    __builtin_amdgcn_wave_barrier();
    if (done < cnt) { batch(done, false); }

    // combine the 4 groups (lanes l, l^16, l^32, l^48 hold the same dims)
    #pragma unroll
    for (int m = 16; m <= 32; m <<= 1) {
        acc0.x += __shfl_xor(acc0.x, m, 64); acc0.y += __shfl_xor(acc0.y, m, 64);
        acc0.z += __shfl_xor(acc0.z, m, 64); acc0.w += __shfl_xor(acc0.w, m, 64);
        acc1.x += __shfl_xor(acc1.x, m, 64); acc1.y += __shfl_xor(acc1.y, m, 64);
        acc1.z += __shfl_xor(acc1.z, m, 64); acc1.w += __shfl_xor(acc1.w, m, 64);
        dn     += __shfl_xor(dn,     m, 64);
    }

    float inv = 1.0f / dn;
    if (g == 0) {                              // 16 lanes write 512 B
        float* orow = out + (size_t)row * GD + t * 8;
        f32x4 o0 = {acc0.x * inv, acc0.y * inv, acc0.z * inv, acc0.w * inv};
        f32x4 o1 = {acc1.x * inv, acc1.y * inv, acc1.z * inv, acc1.w * inv};
        *(f32x4*)orow = o0;
        *(f32x4*)(orow + 4) = o1;
    }
}

extern "C" void kernel_launch(void* const* d_in, const int* in_sizes, int n_in,
                              void* d_out, int out_size, void* d_ws, size_t ws_size,
                              hipStream_t stream) {
    const float* x    = (const float*)d_in[0];
    const float* adj  = (const float*)d_in[1];
    const float* beta = (const float*)d_in[2];
    float* out = (float*)d_out;

    gat_fused<<<GN / WPB, 256, 0, stream>>>(x, adj, beta, out);
}